// Round 1
// 611.805 us; speedup vs baseline: 1.0502x; 1.0502x over previous
//
#include <hip/hip_runtime.h>
#include <stdint.h>

// Problem constants (B=2, D_MODEL=256, C=64, T=1024, H=8, F=32)
// Inputs fp32, output fp32. Intermediates bf16. GEMMs on MFMA bf16.
#define D_MODEL 256
#define TDIM    1024
#define NHEADS  8
#define FDIM    32
#define P_LEN   65536      // C*T positions per batch
#define K3      768        // 3*D_MODEL
#define BK      64         // K-tile per LDS stage

using u16 = unsigned short;

typedef __bf16 bf16x8 __attribute__((ext_vector_type(8)));
typedef float  floatx4 __attribute__((ext_vector_type(4)));

__device__ __forceinline__ float b2f(u16 u) {
    union { float f; uint32_t i; } v; v.i = ((uint32_t)u) << 16; return v.f;
}
__device__ __forceinline__ float b2f_lo(uint32_t u) {
    union { float f; uint32_t i; } v; v.i = u << 16; return v.f;
}
__device__ __forceinline__ float b2f_hi(uint32_t u) {
    union { float f; uint32_t i; } v; v.i = u & 0xffff0000u; return v.f;
}
__device__ __forceinline__ u16 f2b(float f) {
    union { float f; uint32_t i; } v; v.f = f;
    uint32_t i = v.i;
    uint32_t r = i + 0x7fffu + ((i >> 16) & 1u);   // RNE
    return (u16)(r >> 16);
}
__device__ __forceinline__ uint32_t pack2(float lo, float hi) {
    return ((uint32_t)f2b(hi) << 16) | (uint32_t)f2b(lo);
}

// async global->LDS, 16B per lane; lds base must be wave-uniform, lane i
// lands at base + i*16 (guide §5 / m97 / m104).
__device__ __forceinline__ void gload_lds16(const u16* g, u16* l) {
    __builtin_amdgcn_global_load_lds((const __attribute__((address_space(1))) void*)g,
                                     (__attribute__((address_space(3))) void*)l,
                                     16, 0, 0);
}

__device__ __forceinline__ void stc(u16* p, float v) { *p = f2b(v); }
__device__ __forceinline__ void stc(float* p, float v) { *p = v; }

// ---------------------------------------------------------------------------
// 1) InstanceNorm stats: one block per (b,d) row of 65536 fp32 elements.
// ---------------------------------------------------------------------------
__global__ __launch_bounds__(256) void stats_kernel(const float* __restrict__ x,
                                                    float* __restrict__ mu,
                                                    float* __restrict__ rstd) {
    int bd = blockIdx.x;                       // 0..511
    const float* row = x + (size_t)bd * P_LEN;
    int tid = threadIdx.x;
    float s = 0.f, sq = 0.f;
    for (int i = 0; i < P_LEN / (256 * 4); ++i) {
        int idx = (i * 256 + tid) * 4;
        float4 u = *(const float4*)(row + idx);
        s += u.x + u.y + u.z + u.w;
        sq += u.x * u.x + u.y * u.y + u.z * u.z + u.w * u.w;
    }
    for (int off = 32; off; off >>= 1) { s += __shfl_down(s, off); sq += __shfl_down(sq, off); }
    __shared__ float rs[4], rq[4];
    if ((tid & 63) == 0) { rs[tid >> 6] = s; rq[tid >> 6] = sq; }
    __syncthreads();
    if (tid == 0) {
        float S = rs[0] + rs[1] + rs[2] + rs[3];
        float Q = rq[0] + rq[1] + rq[2] + rq[3];
        float m = S * (1.f / 65536.f);
        float var = Q * (1.f / 65536.f) - m * m;
        mu[bd] = m;
        rstd[bd] = rsqrtf(var + 1e-5f);
    }
}

// ---------------------------------------------------------------------------
// 2) Fold norm into QKV weights (bf16) + bias correction (fp32).
// ---------------------------------------------------------------------------
__global__ __launch_bounds__(256) void fold_kernel(const float* __restrict__ in_w,
                                                   const float* __restrict__ in_b,
                                                   const float* __restrict__ mu,
                                                   const float* __restrict__ rstd,
                                                   u16* __restrict__ Wp,
                                                   float* __restrict__ bprime) {
    int bid = blockIdx.x;              // b*768 + e
    int b = bid / K3, e = bid % K3;
    int d = threadIdx.x;
    float w = in_w[e * D_MODEL + d];
    float r = rstd[b * D_MODEL + d];
    float m = mu[b * D_MODEL + d];
    Wp[(size_t)bid * D_MODEL + d] = f2b(w * r);
    float contrib = w * r * m;
    for (int off = 32; off; off >>= 1) contrib += __shfl_down(contrib, off);
    __shared__ float rr[4];
    if ((d & 63) == 0) rr[d >> 6] = contrib;
    __syncthreads();
    if (d == 0) bprime[bid] = in_b[e] - (rr[0] + rr[1] + rr[2] + rr[3]);
}

// ---------------------------------------------------------------------------
// 3) Transpose + bf16 convert: x[d][p] fp32 -> xt[p][d] bf16 (one batch).
//    64x64 tiles through LDS.
// ---------------------------------------------------------------------------
__global__ __launch_bounds__(256) void transpose_x(const float* __restrict__ x,
                                                   u16* __restrict__ xt) {
    __shared__ float tile[64][65];
    int p0 = blockIdx.x * 64;
    int d0 = blockIdx.y * 64;
    int tid = threadIdx.x;
    int dr = tid >> 4;            // 0..15
    int pc = (tid & 15) * 4;      // 0..60
#pragma unroll
    for (int it = 0; it < 4; ++it) {
        int d = it * 16 + dr;
        float4 v = *(const float4*)&x[(size_t)(d0 + d) * P_LEN + p0 + pc];
        tile[pc + 0][d] = v.x;
        tile[pc + 1][d] = v.y;
        tile[pc + 2][d] = v.z;
        tile[pc + 3][d] = v.w;
    }
    __syncthreads();
    int pr = tid >> 3;            // 0..31
    int dc = (tid & 7) * 8;       // 0..56
#pragma unroll
    for (int it = 0; it < 2; ++it) {
        int p = it * 32 + pr;
        ushort4 o0 = make_ushort4(f2b(tile[p][dc + 0]), f2b(tile[p][dc + 1]),
                                  f2b(tile[p][dc + 2]), f2b(tile[p][dc + 3]));
        ushort4 o1 = make_ushort4(f2b(tile[p][dc + 4]), f2b(tile[p][dc + 5]),
                                  f2b(tile[p][dc + 6]), f2b(tile[p][dc + 7]));
        u16* dst = xt + (size_t)(p0 + p) * D_MODEL + d0 + dc;
        *(ushort4*)dst = o0;
        *(ushort4*)(dst + 4) = o1;
    }
}

// ---------------------------------------------------------------------------
// 4) MFMA GEMM: C[M x 65536] = A[M x 256] * Bt[65536 x 256]^T (+bias,+resid)
//    A, Bt bf16 row-major (K contiguous). 128x128 tile, 4 waves, 4x4 MFMA
//    16x16x32 per wave. global_load_lds w/ XOR chunk swizzle (conflict-free
//    b128 fragment reads without LDS padding).
//    PERC: A is per-c (c = blockIdx.x>>3), 256x256 each.
// ---------------------------------------------------------------------------
template <bool RESID, bool PERC, typename OT>
__global__ __launch_bounds__(256) void mgemm(const u16* __restrict__ A,
                                             const u16* __restrict__ Bt,
                                             const float* __restrict__ bias,
                                             const float* __restrict__ resid,
                                             OT* __restrict__ Cout) {
    __shared__ __align__(16) u16 As[128 * BK];   // [m][k] swizzled, 16 KB
    __shared__ __align__(16) u16 Bs[128 * BK];   // [n][k] swizzled, 16 KB
    const int tid  = threadIdx.x;
    const int wave = tid >> 6;
    const int lane = tid & 63;
    const int m0 = blockIdx.y * 128;
    const int p0 = blockIdx.x * 128;
    const int mw = (wave >> 1) * 64;
    const int nw = (wave & 1) * 64;

    const u16* Ab = PERC ? A + ((size_t)(blockIdx.x >> 3) << 16) : A;

    floatx4 acc[4][4];
#pragma unroll
    for (int i = 0; i < 4; ++i)
#pragma unroll
        for (int j = 0; j < 4; ++j) acc[i][j] = (floatx4){0.f, 0.f, 0.f, 0.f};

    const int srow = lane >> 3;      // 0..7 (row within 8-row group)
    const int schunk = lane & 7;     // 0..7 (16B chunk within 128B row)
    const int q  = lane >> 4;        // quad 0..3
    const int rl = lane & 15;

    for (int s = 0; s < 4; ++s) {
        const int k0 = s * BK;
#pragma unroll
        for (int j = 0; j < 4; ++j) {
            int rbase = wave * 32 + j * 8;            // wave-uniform
            int r = rbase + srow;
            int cg = schunk ^ (r & 7);                // swizzle on global side
            gload_lds16(Ab + ((size_t)(m0 + r) << 8) + k0 + cg * 8, &As[rbase * BK]);
            gload_lds16(Bt + ((size_t)(p0 + r) << 8) + k0 + cg * 8, &Bs[rbase * BK]);
        }
        __syncthreads();   // drains vmcnt before barrier (compiler-inserted)
#pragma unroll
        for (int ks = 0; ks < 2; ++ks) {
            bf16x8 af[4], bf[4];
#pragma unroll
            for (int ti = 0; ti < 4; ++ti) {
                int r = mw + 16 * ti + rl;
                int cp = (ks * 4 + q) ^ (r & 7);
                af[ti] = *(const bf16x8*)&As[r * BK + cp * 8];
            }
#pragma unroll
            for (int tj = 0; tj < 4; ++tj) {
                int r = nw + 16 * tj + rl;
                int cp = (ks * 4 + q) ^ (r & 7);
                bf[tj] = *(const bf16x8*)&Bs[r * BK + cp * 8];
            }
#pragma unroll
            for (int ti = 0; ti < 4; ++ti)
#pragma unroll
                for (int tj = 0; tj < 4; ++tj)
                    acc[ti][tj] = __builtin_amdgcn_mfma_f32_16x16x32_bf16(
                        af[ti], bf[tj], acc[ti][tj], 0, 0, 0);
        }
        __syncthreads();
    }

    // Epilogue. C/D layout: col = lane&15 (n), row = quad*4 + reg (m).
#pragma unroll
    for (int ti = 0; ti < 4; ++ti) {
#pragma unroll
        for (int i = 0; i < 4; ++i) {
            int e = m0 + mw + 16 * ti + 4 * q + i;
            float bv = bias[e];
            size_t rowbase = (size_t)e * P_LEN + p0 + nw;
#pragma unroll
            for (int tj = 0; tj < 4; ++tj) {
                size_t addr = rowbase + 16 * tj + rl;
                float v = acc[ti][tj][i] + bv;
                if (RESID) v += resid[addr];
                stc(Cout + addr, v);
            }
        }
    }
}

// ---------------------------------------------------------------------------
// 5) q feature-softmax, streaming: reads q[e][p] (rows 0..255 of qkv),
//    writes Pq[p][256] bf16 (d contiguous) for mgemm2. Each block owns ALL
//    8 heads of 128 positions -> every 128B output line written whole
//    (no partial-line RMW). No max-subtraction: |q| small, exp fp32-safe,
//    softmax ratio unchanged.
// ---------------------------------------------------------------------------
__global__ __launch_bounds__(256) void qsm_kernel(const u16* __restrict__ qkv,
                                                  u16* __restrict__ pq) {
    int tid = threadIdx.x;
    int pair = tid >> 2;              // 0..63  -> positions p, p+1
    int hq = tid & 3;                 // heads hq*2, hq*2+1
    size_t p = (size_t)blockIdx.x * 128 + (size_t)pair * 2;
    const u16* qb = qkv + p;
#pragma unroll
    for (int hi = 0; hi < 2; ++hi) {
        int h = hq * 2 + hi;
        const u16* qh = qb + (size_t)(h * FDIM) * P_LEN;
        float a[32], b[32];
#pragma unroll
        for (int f = 0; f < 32; ++f) {
            uint32_t uu = *(const uint32_t*)(qh + (size_t)f * P_LEN);
            a[f] = __expf(b2f_lo(uu));
            b[f] = __expf(b2f_hi(uu));
        }
        float sa = 0.f, sb = 0.f;
#pragma unroll
        for (int f = 0; f < 32; ++f) { sa += a[f]; sb += b[f]; }
        sa = 1.f / sa; sb = 1.f / sb;
        u16* o1 = pq + p * D_MODEL + h * FDIM;
        u16* o2 = o1 + D_MODEL;
#pragma unroll
        for (int c = 0; c < 4; ++c) {
            union { u16 u[8]; uint4 v4; } pka, pkb;
#pragma unroll
            for (int i = 0; i < 8; ++i) {
                pka.u[i] = f2b(a[c * 8 + i] * sa);
                pkb.u[i] = f2b(b[c * 8 + i] * sb);
            }
            *(uint4*)(o1 + c * 8) = pka.v4;
            *(uint4*)(o2 + c * 8) = pkb.v4;
        }
    }
}

// ---------------------------------------------------------------------------
// 6) ctx kernel: per (c,h): ctx[k][v] = sum_t softmax_t(K)[k,t] * V[v,t],
//    with scale/(s*T) folded into the exp'd K rows. MFMA 16x16x32 over
//    K=1024 in 4 staged chunks; LDS rows padded to 264 u16 (528B = 33*16B,
//    uniform bank spread for b128 reads/writes). Output fp32 [c][h][32][32].
// ---------------------------------------------------------------------------
__global__ __launch_bounds__(256) void ctx_kernel(const u16* __restrict__ qkv,
                                                  float* __restrict__ ctx) {
    int bid = blockIdx.x;              // 0..511
    int c = bid >> 3, h = bid & 7;
    int tid = threadIdx.x;
    size_t colbase = (size_t)c * TDIM;
    const u16* kb = qkv + (size_t)(D_MODEL + h * FDIM) * P_LEN + colbase;
    const u16* vb = qkv + (size_t)(2 * D_MODEL + h * FDIM) * P_LEN + colbase;

    __shared__ float kinv[32];
    __shared__ __align__(16) u16 ekt[32 * 264];
    __shared__ __align__(16) u16 vsb[32 * 264];

    // phase 1: per-row sum of exp(k) (no max-sub: |k| small, fp32-safe)
    {
        int row = tid >> 3, g = tid & 7;
        const u16* krow = kb + (size_t)row * P_LEN;
        float s = 0.f;
#pragma unroll
        for (int i = 0; i < 16; ++i) {
            uint4 u = *(const uint4*)(krow + g * 8 + i * 64);
            s += __expf(b2f_lo(u.x)) + __expf(b2f_hi(u.x))
               + __expf(b2f_lo(u.y)) + __expf(b2f_hi(u.y))
               + __expf(b2f_lo(u.z)) + __expf(b2f_hi(u.z))
               + __expf(b2f_lo(u.w)) + __expf(b2f_hi(u.w));
        }
        for (int off = 4; off; off >>= 1) s += __shfl_down(s, off, 8);
        // fold softmax denom, 1/T (v/t) and q-scale 1/sqrt(32) here
        if (g == 0) kinv[row] = 0.17677669529663687f / (s * 1024.f);
    }
    __syncthreads();

    const int lane = tid & 63;
    const int wave = tid >> 6;
    const int rl = lane & 15, q = lane >> 4;
    const int mi = wave >> 1, ni = wave & 1;
    const int o  = tid & 31;           // 16B chunk within 512B row-chunk
    const int r8 = tid >> 5;           // 0..7
    floatx4 acc = {0.f, 0.f, 0.f, 0.f};

    for (int ch = 0; ch < 4; ++ch) {
        int t0 = ch * 256;
        if (ch) __syncthreads();       // protect LDS before restaging
#pragma unroll
        for (int pass = 0; pass < 4; ++pass) {
            int r = pass * 8 + r8;
            float iv = kinv[r];
            uint4 u = *((const uint4*)(kb + (size_t)r * P_LEN + t0) + o);
            uint4 w = *((const uint4*)(vb + (size_t)r * P_LEN + t0) + o);
            uint4 E;
            E.x = pack2(__expf(b2f_lo(u.x)) * iv, __expf(b2f_hi(u.x)) * iv);
            E.y = pack2(__expf(b2f_lo(u.y)) * iv, __expf(b2f_hi(u.y)) * iv);
            E.z = pack2(__expf(b2f_lo(u.z)) * iv, __expf(b2f_hi(u.z)) * iv);
            E.w = pack2(__expf(b2f_lo(u.w)) * iv, __expf(b2f_hi(u.w)) * iv);
            *(uint4*)&ekt[r * 264 + o * 8] = E;
            *(uint4*)&vsb[r * 264 + o * 8] = w;
        }
        __syncthreads();
#pragma unroll
        for (int ks = 0; ks < 8; ++ks) {
            bf16x8 a  = *(const bf16x8*)&ekt[(16 * mi + rl) * 264 + ks * 32 + q * 8];
            bf16x8 bv = *(const bf16x8*)&vsb[(16 * ni + rl) * 264 + ks * 32 + q * 8];
            acc = __builtin_amdgcn_mfma_f32_16x16x32_bf16(a, bv, acc, 0, 0, 0);
        }
    }

    // C/D layout: col = lane&15 (n = v), row = 4q + i (m = k)
    float* co = ctx + (size_t)bid * 1024;
#pragma unroll
    for (int i = 0; i < 4; ++i)
        co[(16 * mi + 4 * q + i) * 32 + 16 * ni + rl] = acc[i];
}

// ---------------------------------------------------------------------------
// 7) Fold ctx into out-projection: W2'_c[e][h*32+k] = sum_v W2[e][h*32+v] *
//    ctx[c][h][k][v], bf16 out. Grid (64 c, 2 e-halves).
// ---------------------------------------------------------------------------
__global__ __launch_bounds__(256) void wfold_kernel(const float* __restrict__ w2,
                                                    const float* __restrict__ ctx,
                                                    u16* __restrict__ w2p) {
    __shared__ float cs[8192];         // ctx[c][8][32][32]
    int c = blockIdx.x;
    int tid = threadIdx.x;
    const float4* cb = (const float4*)(ctx + (size_t)c * 8192);
#pragma unroll
    for (int i = 0; i < 8; ++i)
        ((float4*)cs)[i * 256 + tid] = cb[i * 256 + tid];
    __syncthreads();
    int e = blockIdx.y * 128 + (tid >> 1);
    int hh = tid & 1;
    const float* wrow = w2 + (size_t)e * 256;
    u16* orow = w2p + ((size_t)c << 16) + (size_t)e * 256;
#pragma unroll
    for (int hi = 0; hi < 4; ++hi) {
        int h = hh * 4 + hi;
        float w[32];
#pragma unroll
        for (int v = 0; v < 8; ++v) {
            float4 t4 = *(const float4*)&wrow[h * 32 + v * 4];
            w[v * 4 + 0] = t4.x; w[v * 4 + 1] = t4.y;
            w[v * 4 + 2] = t4.z; w[v * 4 + 3] = t4.w;
        }
        const float* chp = cs + h * 1024;
#pragma unroll
        for (int kc = 0; kc < 4; ++kc) {
            union { u16 u[8]; uint4 v4; } pk;
#pragma unroll
            for (int ki = 0; ki < 8; ++ki) {
                const float* ck = chp + (kc * 8 + ki) * 32;
                float acc = 0.f;
#pragma unroll
                for (int v = 0; v < 32; v += 4) {
                    float4 c4 = *(const float4*)&ck[v];
                    acc += w[v] * c4.x + w[v + 1] * c4.y
                         + w[v + 2] * c4.z + w[v + 3] * c4.w;
                }
                pk.u[ki] = f2b(acc);
            }
            *(uint4*)(orow + h * 32 + kc * 8) = pk.v4;
        }
    }
}

// ---------------------------------------------------------------------------
// Workspace layout (bytes):
//   mu      [512]  f32            @ 0
//   rstd    [512]  f32            @ 2048
//   Wp      [1536*256] bf16       @ 4096        (786432)
//   bprime  [1536] f32            @ 790528      (6144)
//   tbuf    [65536*256] bf16      @ 796672      (33554432)  xbT / Pq (aliased)
//   qkvb    [768*65536] bf16      @ 34351104    (100663296) reused per batch
//     ctx  = qkvb + 0       (2 MB, fp32 [64][8][32][32]) -- q region, dead
//     w2p  = qkvb + 4 MB    (8 MB, bf16 [64][256][256])     after qsm_kernel
// total = 135014400 bytes (<= previous 135145472)
// ---------------------------------------------------------------------------
extern "C" void kernel_launch(void* const* d_in, const int* in_sizes, int n_in,
                              void* d_out, int out_size, void* d_ws, size_t ws_size,
                              hipStream_t stream) {
    const float* x     = (const float*)d_in[0];
    const float* in_w  = (const float*)d_in[1];
    const float* in_b  = (const float*)d_in[2];
    const float* out_w = (const float*)d_in[3];
    const float* out_b = (const float*)d_in[4];
    float* out = (float*)d_out;

    char* ws = (char*)d_ws;
    float* mu     = (float*)(ws);
    float* rstd   = (float*)(ws + 2048);
    u16*   Wp     = (u16*)(ws + 4096);
    float* bprime = (float*)(ws + 790528);
    u16*   tbuf   = (u16*)(ws + 796672);
    u16*   qkvb   = (u16*)(ws + 34351104);
    float* ctxb   = (float*)(ws + 34351104);             // aliases dead q rows
    u16*   w2p    = (u16*)(ws + 34351104 + 4194304);     // aliases dead q rows

    stats_kernel<<<512, 256, 0, stream>>>(x, mu, rstd);
    fold_kernel<<<1536, 256, 0, stream>>>(in_w, in_b, mu, rstd, Wp, bprime);

    for (int b = 0; b < 2; ++b) {
        const float* xb = x + (size_t)b * D_MODEL * P_LEN;
        transpose_x<<<dim3(1024, 4), 256, 0, stream>>>(xb, tbuf);
        mgemm<false, false, u16><<<dim3(512, 6), 256, 0, stream>>>(
            Wp + (size_t)b * K3 * D_MODEL, tbuf, bprime + b * K3, nullptr, qkvb);
        // q region of qkvb is dead after qsm_kernel; ctx/w2p alias into it.
        qsm_kernel<<<512, 256, 0, stream>>>(qkvb, tbuf);
        ctx_kernel<<<512, 256, 0, stream>>>(qkvb, ctxb);
        wfold_kernel<<<dim3(64, 2), 256, 0, stream>>>(out_w, ctxb, w2p);
        mgemm<true, true, float><<<dim3(512, 2), 256, 0, stream>>>(
            w2p, tbuf, out_b, xb, out + (size_t)b * D_MODEL * P_LEN);
    }
}